// Round 7
// baseline (64.168 us; speedup 1.0000x reference)
//
#include <hip/hip_runtime.h>

// B=8, N=16384, E=64, F=64. Positions = B*N = 131072.
// Y[f, (p,i)] = sum_{k=0..191} Mcat[f][k] * T[p][k][i];  Mcat = [A|Bw|C].
// R7: wave-independent design. Each 64-thread block = 1 wave owning 4
// positions/iter across ALL 64 f-rows (all 24 Mcat fragments in VGPRs).
// LDS is wave-private -> ZERO __syncthreads. Same-wave DS ordering + compiler
// waitcnt provide all needed hazards. Ys staging XOR-swizzled (R6: 3.9M
// conflicts from pl2-independent banks).

#define NPOS   131072
#define PPW    4                     // positions per iteration
#define ITERS  8
#define BLOCKS (NPOS / (PPW * ITERS))   // 4096 single-wave blocks
#define THREADS 64

typedef _Float16 half8 __attribute__((ext_vector_type(8)));
typedef float floatx4 __attribute__((ext_vector_type(4)));

__global__ __launch_bounds__(THREADS, 2)
void fused_wave(const float* __restrict__ X, const float* __restrict__ J,
                const float* __restrict__ A, const float* __restrict__ Bw,
                const float* __restrict__ Cm, float* __restrict__ Y) {
    // Terms: kappa = ks*32 + kg*8 + j; kg slot XOR-swizzled by ((n>>1)&3)
    // (verified 0-conflict in R4/R5). Cols 12..15 unused garbage (finite or
    // not, their MFMA columns are never stored).
    __shared__ _Float16 Tl[6][16][4][8];   // 6144 B
    // Y staging: logical = block's contiguous 3072B Y slice; physical 16B
    // chunks XOR-permuted: c' = c ^ ((c>>4)&15) (involution within 256B).
    __shared__ float Ys[PPW * 192];        // 3072 B  (9216 B/block total)

    const int lane = threadIdx.x;

    // ---- All 24 Mcat fragments in registers (96 VGPR), whole kernel.
    // afrag[ft][ks]: lane holds Mcat[f=ft*16+(l&15)][k=ks*32+(l>>4)*8+j].
    const int fr  = lane & 15;
    const int kgA = lane >> 4;
    half8 afrag[4][6];
    #pragma unroll
    for (int ft = 0; ft < 4; ++ft) {
        #pragma unroll
        for (int ks = 0; ks < 6; ++ks) {
            const float* mat = (ks < 2) ? A : (ks < 4 ? Bw : Cm);
            const float* src = mat + (ft * 16 + fr) * 64 + (ks & 1) * 32 + kgA * 8;
            float4 lo = *(const float4*)src;
            float4 hi = *(const float4*)(src + 4);
            half8 h;
            h[0] = (_Float16)lo.x; h[1] = (_Float16)lo.y;
            h[2] = (_Float16)lo.z; h[3] = (_Float16)lo.w;
            h[4] = (_Float16)hi.x; h[5] = (_Float16)hi.y;
            h[6] = (_Float16)hi.z; h[7] = (_Float16)hi.w;
            afrag[ft][ks] = h;
        }
    }

    // P1 write coords (e = lane): ks = 2t + (e>>5), kg = (e&31)>>3, j = e&7.
    const int ks0 = lane >> 5;
    const int kgW = (lane & 31) >> 3;
    const int jW  = lane & 7;
    // P2 B-frag read slot (swizzle-corrected).
    const int kgR = (lane >> 4) ^ (((lane & 15) >> 1) & 3);

    const int p0 = blockIdx.x * (PPW * ITERS);

    float jr[PPW][3], xr[PPW][3];    // prefetch registers (static-indexed)

    auto LOAD = [&](int t) {
        #pragma unroll
        for (int q = 0; q < PPW; ++q) {
            const int p = p0 + t * PPW + q;
            const float* jp = J + (size_t)(p * 64 + lane) * 3;
            const float* xp = X + (size_t)(p * 64 + lane) * 3;
            jr[q][0] = jp[0]; jr[q][1] = jp[1]; jr[q][2] = jp[2];
            xr[q][0] = xp[0]; xr[q][1] = xp[1]; xr[q][2] = xp[2];
        }
    };

    auto P1 = [&]() {
        #pragma unroll
        for (int q = 0; q < PPW; ++q) {
            float ja = jr[q][0], jb = jr[q][1], jg = jr[q][2];
            float x0 = xr[q][0], x1 = xr[q][1], x2 = xr[q][2];
            float sa, ca, sb, cb, sg, cg;
            __sincosf(ja, &sa, &ca);
            __sincosf(jb, &sb, &cb);
            __sincosf(jg, &sg, &cg);
            float casb = ca * sb, sasb = sa * sb;
            float r00 = ca * cb, r01 = casb * sg - sa * cg, r02 = casb * cg + sa * sg;
            float r10 = sa * cb, r11 = sasb * sg + ca * cg, r12 = sasb * cg - ca * sg;
            float r20 = -sb,     r21 = cb * sg,             r22 = cb * cg;
            float v0 = fmaf(r00, x0, fmaf(r10, x1, r20 * x2));
            float v1 = fmaf(r01, x0, fmaf(r11, x1, r21 * x2));
            float v2 = fmaf(r02, x0, fmaf(r12, x1, r22 * x2));
            float ta[3], tb[3], tc[3];
            ta[0] = fmaf(r00, v0, r01 * v1);
            ta[1] = fmaf(r10, v0, r11 * v1);
            ta[2] = fmaf(r20, v0, r21 * v1);
            tb[0] = fmaf(r01, v0, -r00 * v1);
            tb[1] = fmaf(r11, v0, -r10 * v1);
            tb[2] = fmaf(r21, v0, -r20 * v1);
            tc[0] = r02 * v2; tc[1] = r12 * v2; tc[2] = r22 * v2;

            #pragma unroll
            for (int i = 0; i < 3; ++i) {
                const int n  = q * 3 + i;               // 12 cols per wave
                const int kg = kgW ^ ((n >> 1) & 3);    // swizzled slot
                Tl[0 + ks0][n][kg][jW] = (_Float16)ta[i];
                Tl[2 + ks0][n][kg][jW] = (_Float16)tb[i];
                Tl[4 + ks0][n][kg][jW] = (_Float16)tc[i];
            }
        }
    };

    auto P2 = [&]() {
        floatx4 acc[4];
        #pragma unroll
        for (int ft = 0; ft < 4; ++ft) acc[ft] = (floatx4){0.f, 0.f, 0.f, 0.f};
        #pragma unroll
        for (int ks = 0; ks < 6; ++ks) {
            half8 b = *(const half8*)&Tl[ks][lane & 15][kgR][0];   // shared by all ft
            #pragma unroll
            for (int ft = 0; ft < 4; ++ft)
                acc[ft] = __builtin_amdgcn_mfma_f32_16x16x32_f16(afrag[ft][ks], b, acc[ft], 0, 0, 0);
        }
        // Stage acc -> Ys (swizzled). Cols n >= 12 are padding, not stored.
        const int n = lane & 15;
        if (n < 12) {
            const int pl2 = (n * 171) >> 9;     // n/3
            const int i2  = n - pl2 * 3;
            #pragma unroll
            for (int ft = 0; ft < 4; ++ft) {
                const int f0 = ft * 16 + (lane >> 4) * 4;
                #pragma unroll
                for (int r = 0; r < 4; ++r) {
                    const int z  = pl2 * 192 + (f0 + r) * 3 + i2;   // logical dword
                    const int c  = z >> 2;
                    const int zp = (((c ^ ((c >> 4) & 15))) << 2) | (z & 3);
                    Ys[zp] = acc[ft][r];
                }
            }
        }
    };

    auto STORE_Y = [&](int t) {
        float* yb = Y + (size_t)(p0 + t * PPW) * 192;
        #pragma unroll
        for (int k = 0; k < 3; ++k) {
            const int c  = lane + 64 * k;            // logical 16B chunk
            const int cp = c ^ ((c >> 4) & 15);      // physical chunk
            floatx4 v = *(const floatx4*)&Ys[cp * 4];
            __builtin_nontemporal_store(v, (floatx4*)(yb + (size_t)c * 4));
        }
    };

    // ---- Barrier-free stream: same-wave DS ordering covers all LDS hazards.
    LOAD(0);
    for (int t = 0; t < ITERS; ++t) {
        P1();                              // consume jr/xr, write Tl
        if (t + 1 < ITERS) LOAD(t + 1);    // prefetch; latency hides under P2+STORE
        P2();                              // read Tl, MFMA, write Ys
        STORE_Y(t);                        // read Ys, coalesced nt store
    }
}

extern "C" void kernel_launch(void* const* d_in, const int* in_sizes, int n_in,
                              void* d_out, int out_size, void* d_ws, size_t ws_size,
                              hipStream_t stream) {
    const float* X  = (const float*)d_in[0];
    const float* J  = (const float*)d_in[1];
    const float* A  = (const float*)d_in[2];
    const float* Bw = (const float*)d_in[3];
    const float* Cm = (const float*)d_in[4];
    float* Y = (float*)d_out;
    fused_wave<<<BLOCKS, THREADS, 0, stream>>>(X, J, A, Bw, Cm, Y);
}